// Round 3
// baseline (507.612 us; speedup 1.0000x reference)
//
#include <hip/hip_runtime.h>

// AdultConnectomeNetwork: 3 layers of xt = A_sp @ (W_sp @ xt) + bias.
// Round 3: (1) scatter payload packed into one float4 store/edge (one dirty
// line per edge instead of three), (2) parallel block-sum scan (was a
// single-thread serial loop), (3) SpMM unroll-8 for more MLP + single 16B
// broadcast load per edge. Falls back to split-array layout if ws is small.
// State layout: xt[N][32] (one 128B line per neuron).

#define NN 50000
#define NNZ_E 1600000
#define NB (NN * 32)
#define SCAN_BS 256
#define NBLK ((NN + SCAN_BS - 1) / SCAN_BS)   // 196

__global__ void zero_counts_kernel(int* __restrict__ counts) {
    int i = blockIdx.x * blockDim.x + threadIdx.x;
    if (i < NN) counts[i] = 0;
}

__global__ void hist_kernel(const int* __restrict__ row, int* __restrict__ counts) {
    int e = blockIdx.x * blockDim.x + threadIdx.x;
    if (e < NNZ_E) atomicAdd(&counts[row[e]], 1);
}

// In-place: counts[i] -> exclusive-scan-within-block; bsum[blk] = block total.
__global__ void scan_block_kernel(int* __restrict__ data, int* __restrict__ bsum) {
    __shared__ int s[SCAN_BS];
    int i = blockIdx.x * SCAN_BS + threadIdx.x;
    int v = (i < NN) ? data[i] : 0;
    s[threadIdx.x] = v;
    __syncthreads();
    for (int off = 1; off < SCAN_BS; off <<= 1) {
        int t = (threadIdx.x >= off) ? s[threadIdx.x - off] : 0;
        __syncthreads();
        s[threadIdx.x] += t;
        __syncthreads();
    }
    if (i < NN) data[i] = s[threadIdx.x] - v;              // exclusive within block
    if (threadIdx.x == SCAN_BS - 1) bsum[blockIdx.x] = s[threadIdx.x];
}

// Parallel exclusive scan of bsum[NBLK] (NBLK=196 <= 256), one block.
__global__ void scan_bsum_kernel(int* __restrict__ bsum) {
    __shared__ int s[SCAN_BS];
    int t = threadIdx.x;
    int v = (t < NBLK) ? bsum[t] : 0;
    s[t] = v;
    __syncthreads();
    for (int off = 1; off < SCAN_BS; off <<= 1) {
        int u = (t >= off) ? s[t - off] : 0;
        __syncthreads();
        s[t] += u;
        __syncthreads();
    }
    if (t < NBLK) bsum[t] = s[t] - v;                      // exclusive
}

__global__ void scan_finalize_kernel(const int* __restrict__ excl,
                                     const int* __restrict__ boff,
                                     int* __restrict__ row_start,
                                     int* __restrict__ cursor) {
    int i = blockIdx.x * blockDim.x + threadIdx.x;
    if (i < NN) {
        int v = excl[i] + boff[i / SCAN_BS];
        row_start[i] = v;
        cursor[i] = v;
    }
    if (i == 0) row_start[NN] = NNZ_E;
}

// ---- packed path: one float4 store per edge ----
__global__ void scatter_packed_kernel(const int* __restrict__ row,
                                      const int* __restrict__ col,
                                      const float* __restrict__ a,
                                      const float* __restrict__ w,
                                      int* __restrict__ cursor,
                                      float4* __restrict__ pk) {
    int e = blockIdx.x * blockDim.x + threadIdx.x;
    if (e < NNZ_E) {
        int r = row[e];
        int pos = atomicAdd(&cursor[r], 1);
        float4 p;
        p.x = __int_as_float(col[e] << 5);   // pre-shifted col*32
        p.y = a[e];
        p.z = w[e];
        p.w = 0.0f;
        pk[pos] = p;
    }
}

// SEL==0: W-pass (uses .z, acc starts 0). SEL==1: A-pass (uses .y, +bias).
template <int SEL>
__global__ __launch_bounds__(256) void spmm_packed_kernel(
        const float4* __restrict__ pk, const int* __restrict__ row_start,
        const float* __restrict__ in, float* __restrict__ out,
        const float* __restrict__ bias) {
    int t = blockIdx.x * blockDim.x + threadIdx.x;
    int r = t >> 5;
    int b = t & 31;
    if (r >= NN) return;
    int s = row_start[r];
    int e = row_start[r + 1];
    float acc = (SEL == 0) ? 0.0f : bias[r];
    int i = s;
    for (; i + 8 <= e; i += 8) {
        float4 p[8];
#pragma unroll
        for (int j = 0; j < 8; ++j) p[j] = pk[i + j];
        float g[8];
#pragma unroll
        for (int j = 0; j < 8; ++j) g[j] = in[__float_as_int(p[j].x) + b];
#pragma unroll
        for (int j = 0; j < 8; ++j) acc += ((SEL == 0) ? p[j].z : p[j].y) * g[j];
    }
    for (; i < e; ++i) {
        float4 p = pk[i];
        acc += ((SEL == 0) ? p.z : p.y) * in[__float_as_int(p.x) + b];
    }
    out[(r << 5) + b] = acc;
}

// ---- split fallback (round-2 layout, unroll 8) ----
__global__ void scatter_split_kernel(const int* __restrict__ row, const int* __restrict__ col,
                                     const float* __restrict__ a, const float* __restrict__ w,
                                     int* __restrict__ cursor,
                                     int* __restrict__ col_s, float* __restrict__ a_s,
                                     float* __restrict__ w_s) {
    int e = blockIdx.x * blockDim.x + threadIdx.x;
    if (e < NNZ_E) {
        int r = row[e];
        int pos = atomicAdd(&cursor[r], 1);
        col_s[pos] = col[e] << 5;
        a_s[pos]   = a[e];
        w_s[pos]   = w[e];
    }
}

__global__ __launch_bounds__(256) void spmm_split_kernel(
        const float* __restrict__ vals, const int* __restrict__ col_s,
        const int* __restrict__ row_start, const float* __restrict__ in,
        float* __restrict__ out, const float* __restrict__ bias) {
    int t = blockIdx.x * blockDim.x + threadIdx.x;
    int r = t >> 5;
    int b = t & 31;
    if (r >= NN) return;
    int s = row_start[r];
    int e = row_start[r + 1];
    float acc = bias ? bias[r] : 0.0f;
    int i = s;
    for (; i + 8 <= e; i += 8) {
        int c[8]; float v[8]; float g[8];
#pragma unroll
        for (int j = 0; j < 8; ++j) { c[j] = col_s[i + j]; v[j] = vals[i + j]; }
#pragma unroll
        for (int j = 0; j < 8; ++j) g[j] = in[c[j] + b];
#pragma unroll
        for (int j = 0; j < 8; ++j) acc += v[j] * g[j];
    }
    for (; i < e; ++i)
        acc += vals[i] * in[col_s[i] + b];
    out[(r << 5) + b] = acc;
}

__global__ void transpose_in_kernel(const float* __restrict__ x,
                                    float* __restrict__ xt) {
    int i = blockIdx.x * blockDim.x + threadIdx.x;  // i = n*32 + b
    if (i < NB) {
        int n = i >> 5;
        int b = i & 31;
        xt[i] = x[b * NN + n];
    }
}

__global__ void transpose_out_kernel(const float* __restrict__ xt,
                                     float* __restrict__ out) {
    int i = blockIdx.x * blockDim.x + threadIdx.x;  // i = b*N + n (coalesced write)
    if (i < NB) {
        int b = i / NN;
        int n = i - b * NN;
        out[i] = xt[(n << 5) + b];
    }
}

extern "C" void kernel_launch(void* const* d_in, const int* in_sizes, int n_in,
                              void* d_out, int out_size, void* d_ws, size_t ws_size,
                              hipStream_t stream) {
    const float* x        = (const float*)d_in[0];
    const float* adj_vals = (const float*)d_in[1];
    const float* w_vals   = (const float*)d_in[2];
    const float* bias     = (const float*)d_in[3];
    const int*   row      = (const int*)d_in[4];
    const int*   col      = (const int*)d_in[5];
    float* out = (float*)d_out;

    const int BS = 256;
    const int grid_n    = (NN + BS - 1) / BS;
    const int grid_nb   = (NB + BS - 1) / BS;
    const int grid_edge = (NNZ_E + BS - 1) / BS;

    // Packed layout: pk[NNZ_E] float4 | xt[NB] | tmp[NB] | ints
    const size_t packed_need =
        (size_t)NNZ_E * 16 + (size_t)NB * 8 + ((size_t)NN * 3 + 8 + NBLK) * 4;
    const bool use_packed = ws_size >= packed_need;   // constant across calls

    if (use_packed) {
        float4* pk       = (float4*)d_ws;
        float*  xt       = (float*)(pk + NNZ_E);
        float*  tmp      = xt + NB;
        int*    counts   = (int*)(tmp + NB);
        int*    row_start= counts + NN;
        int*    cursor   = row_start + NN + 4;
        int*    bsum     = cursor + NN;

        zero_counts_kernel<<<grid_n, BS, 0, stream>>>(counts);
        hist_kernel<<<grid_edge, BS, 0, stream>>>(row, counts);
        scan_block_kernel<<<NBLK, SCAN_BS, 0, stream>>>(counts, bsum);
        scan_bsum_kernel<<<1, SCAN_BS, 0, stream>>>(bsum);
        scan_finalize_kernel<<<grid_n, BS, 0, stream>>>(counts, bsum, row_start, cursor);
        scatter_packed_kernel<<<grid_edge, BS, 0, stream>>>(row, col, adj_vals, w_vals,
                                                            cursor, pk);

        transpose_in_kernel<<<grid_nb, BS, 0, stream>>>(x, xt);
        for (int layer = 0; layer < 3; ++layer) {
            spmm_packed_kernel<0><<<grid_nb, BS, 0, stream>>>(pk, row_start, xt, tmp, nullptr);
            spmm_packed_kernel<1><<<grid_nb, BS, 0, stream>>>(pk, row_start, tmp, xt, bias);
        }
        transpose_out_kernel<<<grid_nb, BS, 0, stream>>>(xt, out);
    } else {
        float* xt        = (float*)d_ws;
        float* tmp       = xt + NB;
        float* a_s       = tmp + NB;
        float* w_s       = a_s + NNZ_E;
        int*   col_s     = (int*)(w_s + NNZ_E);
        int*   counts    = col_s + NNZ_E;
        int*   row_start = counts + NN;
        int*   cursor    = row_start + NN + 4;
        int*   bsum      = cursor + NN;

        zero_counts_kernel<<<grid_n, BS, 0, stream>>>(counts);
        hist_kernel<<<grid_edge, BS, 0, stream>>>(row, counts);
        scan_block_kernel<<<NBLK, SCAN_BS, 0, stream>>>(counts, bsum);
        scan_bsum_kernel<<<1, SCAN_BS, 0, stream>>>(bsum);
        scan_finalize_kernel<<<grid_n, BS, 0, stream>>>(counts, bsum, row_start, cursor);
        scatter_split_kernel<<<grid_edge, BS, 0, stream>>>(row, col, adj_vals, w_vals,
                                                           cursor, col_s, a_s, w_s);

        transpose_in_kernel<<<grid_nb, BS, 0, stream>>>(x, xt);
        for (int layer = 0; layer < 3; ++layer) {
            spmm_split_kernel<<<grid_nb, BS, 0, stream>>>(w_s, col_s, row_start, xt, tmp, nullptr);
            spmm_split_kernel<<<grid_nb, BS, 0, stream>>>(a_s, col_s, row_start, tmp, xt, bias);
        }
        transpose_out_kernel<<<grid_nb, BS, 0, stream>>>(xt, out);
    }
}